// Round 7
// baseline (373.984 us; speedup 1.0000x reference)
//
#include <hip/hip_runtime.h>
#include <hip/hip_bf16.h>
#include <math.h>

typedef unsigned short ushort_t;
typedef __attribute__((ext_vector_type(8))) short short8;
typedef __attribute__((ext_vector_type(4))) short short4v;
typedef __attribute__((ext_vector_type(4))) float f32x4;
typedef __attribute__((ext_vector_type(2))) unsigned int uint2v;
typedef __attribute__((ext_vector_type(4))) unsigned int uint4v;

#define MFMA16(a, b, c) __builtin_amdgcn_mfma_f32_16x16x32_bf16((a), (b), (c), 0, 0, 0)

__device__ __forceinline__ short8 ld_s8(const void* p) { return *(const short8*)p; }

// R5 post-mortem: v_cvt_pk_bf16_f32 is BANNED (non-RNE, per-element bias ->
// absmax 0.51 through the GEMM chain). R7: round-half-up instead:
//   bf16(x) = (bits(x) + 0x8000) >> 16
// differs from RNE ONLY on exact ties (low16 == 0x8000, p ~ 2^-16), 1 ULP,
// no systematic bias. Pack two via one v_perm_b32 selecting both hi-halves.
__device__ __forceinline__ ushort_t bf_rhu(float x) {
  return (ushort_t)((__builtin_bit_cast(unsigned, x) + 0x8000u) >> 16);
}
__device__ __forceinline__ unsigned pk2_bf16(float lo, float hi) {
  const unsigned a = __builtin_bit_cast(unsigned, lo) + 0x8000u;
  const unsigned b = __builtin_bit_cast(unsigned, hi) + 0x8000u;
  // sel 0x07060302: out bytes {a.2,a.3,b.2,b.3} = (bf16(hi)<<16)|bf16(lo)
  return __builtin_amdgcn_perm(b, a, 0x07060302u);
}

__device__ __forceinline__ void wave_fence() {
  __builtin_amdgcn_fence(__ATOMIC_ACQ_REL, "wavefront");
}

__device__ __forceinline__ void async_ld16(const void* g, void* l) {
  __builtin_amdgcn_global_load_lds(
      (const __attribute__((address_space(1))) unsigned int*)g,
      (__attribute__((address_space(3))) unsigned int*)l, 16, 0, 0);
}

// ---------------- fp32 -> bf16 elementwise convert (8 elems/thread) ----------------
__global__ __launch_bounds__(256) void cvt_k(const float* __restrict__ src,
                                             ushort_t* __restrict__ dst, size_t n8) {
  const size_t i = (size_t)blockIdx.x * 256 + threadIdx.x;
  if (i >= n8) return;
  const size_t base = i * 8;
  const float4 a = ((const float4*)(src + base))[0];
  const float4 b = ((const float4*)(src + base))[1];
  uint4v o;
  o[0] = pk2_bf16(a.x, a.y);
  o[1] = pk2_bf16(a.z, a.w);
  o[2] = pk2_bf16(b.x, b.y);
  o[3] = pk2_bf16(b.z, b.w);
  *(uint4v*)(dst + base) = o;
}

// ---- batched fused transpose+convert: dst_z[C][R] = (bf16)src_z[R][C]^T, z in {0,1} ----
__global__ void transpose_cvt2_k(const float* __restrict__ s0, const float* __restrict__ s1,
                                 ushort_t* __restrict__ d0, ushort_t* __restrict__ d1,
                                 int R, int C) {
  __shared__ ushort_t tile[32][33];
  const float* src = blockIdx.z ? s1 : s0;
  ushort_t* dst = blockIdx.z ? d1 : d0;
  const int bx = blockIdx.x * 32, by = blockIdx.y * 32;
  const int tx = threadIdx.x, ty = threadIdx.y;
#pragma unroll
  for (int i = 0; i < 32; i += 8)
    tile[ty + i][tx] = bf_rhu(src[(size_t)(by + ty + i) * C + bx + tx]);
  __syncthreads();
#pragma unroll
  for (int i = 0; i < 32; i += 8)
    dst[(size_t)(bx + ty + i) * R + by + tx] = tile[tx][ty + i];
}

// ---------------- GEMM: C[M,N] = A[M,K] @ Bt[N,K]^T (+bias), bf16 ins, fp32 acc ----
// T3 minimum-2-phase pipeline (R6-proven). BK=32 double-buffered, 32 KB LDS,
// ONE barrier per K-tile; loads for tile t+1 drained a full compute phase
// later. Static buffers + 2x unroll (loop-invariant LDS addresses, R3).
// T1 bijective XCD swizzle.
#define BM 128
#define BN 128
#define BK 32

__device__ __forceinline__ void st1(float* p, float v) { *p = v; }
__device__ __forceinline__ void st1(__hip_bfloat16* p, float v) {
  *reinterpret_cast<ushort_t*>(p) = bf_rhu(v);
}

__device__ __forceinline__ int2 xcd_swz(int nx) {
  const int id = blockIdx.y * gridDim.x + blockIdx.x;
  const int cpx = (gridDim.x * gridDim.y) >> 3;  // nwg divisible by 8
  const int nid = (id & 7) * cpx + (id >> 3);
  int2 r; r.x = nid % nx; r.y = nid / nx; return r;
}

#define GSTAGE(sA, sB)                                          \
  do {                                                          \
    async_ld16(Ag + (size_t)srow * K + (k0 + scol), (sA) + wb); \
    async_ld16(Ag + (size_t)(srow + 64) * K + (k0 + scol), (sA) + 2048 + wb); \
    async_ld16(Bg + (size_t)srow * K + (k0 + scol), (sB) + wb); \
    async_ld16(Bg + (size_t)(srow + 64) * K + (k0 + scol), (sB) + 2048 + wb); \
    k0 += BK;                                                   \
  } while (0)

#define GCOMP(sA, sB)                                                     \
  do {                                                                    \
    short8 af[4], bfr[4];                                                 \
    _Pragma("unroll") for (int t = 0; t < 4; ++t) {                       \
      af[t] = ld_s8((sA) + (wm + t * 16 + lr) * BK + quad * 8);           \
      bfr[t] = ld_s8((sB) + (wn + t * 16 + lr) * BK + quad * 8);          \
    }                                                                     \
    _Pragma("unroll") for (int tm = 0; tm < 4; ++tm)                      \
        _Pragma("unroll") for (int tn = 0; tn < 4; ++tn)                  \
            acc[tm][tn] = MFMA16(af[tm], bfr[tn], acc[tm][tn]);           \
  } while (0)

template <typename OutT>
__global__ __launch_bounds__(256) void gemm_bt(const ushort_t* __restrict__ A,
                                               const ushort_t* __restrict__ Bt,
                                               OutT* __restrict__ C,
                                               const float* __restrict__ bias,
                                               int M, int N, int K) {
  __shared__ __align__(16) ushort_t sA0[BM * BK];
  __shared__ __align__(16) ushort_t sA1[BM * BK];
  __shared__ __align__(16) ushort_t sB0[BN * BK];
  __shared__ __align__(16) ushort_t sB1[BN * BK];
  const int tid = threadIdx.x;
  const int lane = tid & 63, wave = tid >> 6;
  const int lr = lane & 15, quad = lane >> 4;
  const int2 bid = xcd_swz(gridDim.x);
  const int m0 = bid.y * BM, n0 = bid.x * BN;
  const int wm = (wave >> 1) * 64, wn = (wave & 1) * 64;
  const ushort_t* Ag = A + (size_t)m0 * K;
  const ushort_t* Bg = Bt + (size_t)n0 * K;
  const int srow = tid >> 2, scol = (tid & 3) * 8;
  const int wb = (tid & 192) * 8;

  f32x4 acc[4][4] = {};
  int k0 = 0;

  GSTAGE(sA0, sB0);  // tile 0 -> buf0
  const int NT2 = K >> 6;  // K/64, two tiles per iteration (K % 64 == 0)
#pragma unroll 1
  for (int i2 = 0; i2 < NT2; ++i2) {
    __syncthreads();                 // drain+publish tile 2*i2 (buf0)
    GSTAGE(sA1, sB1);                // tile 2*i2+1 -> buf1
    GCOMP(sA0, sB0);
    __syncthreads();                 // drain+publish tile 2*i2+1 (buf1)
    if (i2 < NT2 - 1) GSTAGE(sA0, sB0);  // tile 2*i2+2 -> buf0
    GCOMP(sA1, sB1);
  }

#pragma unroll
  for (int tm = 0; tm < 4; ++tm) {
    const int row = m0 + wm + tm * 16 + quad * 4;
#pragma unroll
    for (int tn = 0; tn < 4; ++tn) {
      const int col = n0 + wn + tn * 16 + lr;
      const float bv = bias ? bias[col] : 0.0f;
#pragma unroll
      for (int r = 0; r < 4; ++r)
        st1(&C[(size_t)(row + r) * N + col], acc[tm][tn][r] + bv);
    }
  }
}

// -------- fused K+V GEMM: A[4096,768] @ WkvT[2048,768]^T --------
// cols 0..1023 -> KVb[row][col] (K, row-major, stride 2048)
// cols 1024..2047 -> Vt[b][col-1024][m] (V transposed per batch)
__global__ __launch_bounds__(256) void kv_gemm(const ushort_t* __restrict__ A,
                                               const ushort_t* __restrict__ Bt,
                                               ushort_t* __restrict__ KVb,
                                               ushort_t* __restrict__ Vt) {
  const int K = 768;
  __shared__ __align__(16) ushort_t sA0[BM * BK];
  __shared__ __align__(16) ushort_t sA1[BM * BK];
  __shared__ __align__(16) ushort_t sB0[BN * BK];
  __shared__ __align__(16) ushort_t sB1[BN * BK];
  const int tid = threadIdx.x;
  const int lane = tid & 63, wave = tid >> 6;
  const int lr = lane & 15, quad = lane >> 4;
  const int2 bid = xcd_swz(gridDim.x);
  const int m0 = bid.y * BM, n0 = bid.x * BN;
  const int wm = (wave >> 1) * 64, wn = (wave & 1) * 64;
  const ushort_t* Ag = A + (size_t)m0 * K;
  const ushort_t* Bg = Bt + (size_t)n0 * K;
  const int srow = tid >> 2, scol = (tid & 3) * 8;
  const int wb = (tid & 192) * 8;

  f32x4 acc[4][4] = {};
  int k0 = 0;

  GSTAGE(sA0, sB0);
  const int NT2 = K >> 6;  // 12
#pragma unroll 1
  for (int i2 = 0; i2 < NT2; ++i2) {
    __syncthreads();
    GSTAGE(sA1, sB1);
    GCOMP(sA0, sB0);
    __syncthreads();
    if (i2 < NT2 - 1) GSTAGE(sA0, sB0);
    GCOMP(sA1, sB1);
  }

#pragma unroll
  for (int tm = 0; tm < 4; ++tm) {
    const int row = m0 + wm + tm * 16 + quad * 4;  // global context row
    const int b = row >> 10, mloc = row & 1023;
#pragma unroll
    for (int tn = 0; tn < 4; ++tn) {
      const int col = n0 + wn + tn * 16 + lr;  // block-uniform side of 1024
      if (col < 1024) {
#pragma unroll
        for (int r = 0; r < 4; ++r)
          KVb[(size_t)(row + r) * 2048 + col] = bf_rhu(acc[tm][tn][r]);
      } else {
        ushort_t* vp = Vt + ((size_t)b * 1024 + (col - 1024)) * 1024 + mloc;
#pragma unroll
        for (int r = 0; r < 4; ++r)
          vp[r] = bf_rhu(acc[tm][tn][r]);
      }
    }
  }
}

// ---------------- flash attention v9 ----------------
// grid (4096/128, 16 heads, 4 batch), 256 threads. Wave owns 32 q-rows.
// Changes vs v7/R6 (kill the software-RNE P-pack VALU):
//  * P-pack via add+v_perm round-half-up (pk2_bf16): 32x~5 insts -> 48.
//    Numerator and denominator consume the identical packed P (R4
//    cancellation property preserved).
// Pipeline (dbuf + 2x unroll, compile-time buffers), swapped QK^T, ones-MFMA
// row-sum, XOR swizzle, pre-swizzled global source: unchanged.
// LDS = 48 KB -> 3 blocks/CU.
__global__ __launch_bounds__(256) void attn_k(const ushort_t* __restrict__ Q,
                                              const ushort_t* __restrict__ KVb,
                                              const ushort_t* __restrict__ Vt,
                                              __hip_bfloat16* __restrict__ O) {
  __shared__ __align__(16) ushort_t sK0[64 * 64];
  __shared__ __align__(16) ushort_t sK1[64 * 64];
  __shared__ __align__(16) ushort_t sV0[64 * 64];
  __shared__ __align__(16) ushort_t sV1[64 * 64];
  __shared__ __align__(16) ushort_t sP[4 * 32 * 64];
  const int tid = threadIdx.x;
  const int lane = tid & 63, wave = tid >> 6;
  const int lr = lane & 15, quad = lane >> 4;
  const int b = blockIdx.z, h = blockIdx.y;
  const int q0 = blockIdx.x * 128 + wave * 32;
  const int key = (lr & 7) << 4;  // XOR-swizzle key; all read/write rows == lr (mod 8)

  const ushort_t* Qg = Q + ((size_t)b * 4096 + q0 + lr) * 1024 + h * 64;
  short8 qf[2][2];
#pragma unroll
  for (int t = 0; t < 2; ++t) {
    qf[t][0] = ld_s8(Qg + (size_t)t * 16 * 1024 + quad * 8);
    qf[t][1] = ld_s8(Qg + (size_t)t * 16 * 1024 + 32 + quad * 8);
  }
  const ushort_t* Kg = KVb + (size_t)b * 1024 * 2048 + h * 64;   // row stride 2048
  const ushort_t* Vg = Vt + ((size_t)b * 1024 + h * 64) * 1024;  // row stride 1024

  // staging: linear LDS dest (wave-uniform base + lane*16B), swizzled global col
  const int srow = lane >> 3;                // row within the wave's 8-row chunk
  const int scol = ((lane & 7) ^ srow) * 8;  // pre-swizzled 16B column (shorts)
  const ushort_t* k0 = Kg + (size_t)(wave * 8 + srow) * 2048 + scol;
  const ushort_t* v0 = Vg + (size_t)(wave * 8 + srow) * 1024 + scol;
  ushort_t* const dK0 = sK0 + wave * 512;
  ushort_t* const dK1 = sK1 + wave * 512;
  ushort_t* const dV0 = sV0 + wave * 512;
  ushort_t* const dV1 = sV1 + wave * 512;
  ushort_t* const sPw = sP + wave * 2048;  // 32 rows x 64 shorts, per-wave private

  const float c1 = 0.125f * 1.44269504f;
  const float c2 = 16.0f * 1.44269504f;

  // bf16 1.0 = 0x3F80 : ones B-fragment for the P.1 row-sum MFMA
  short8 onesb;
#pragma unroll
  for (int i = 0; i < 8; ++i) onesb[i] = (short)0x3F80;

  f32x4 ls0 = {}, ls1 = {};
  f32x4 o0[4] = {}, o1[4] = {};

#define STAGE(dK, dV)                                  \
  do {                                                 \
    async_ld16(k0, (dK));                              \
    async_ld16(k0 + (size_t)32 * 2048, (dK) + 2048);   \
    async_ld16(v0, (dV));                              \
    async_ld16(v0 + (size_t)32 * 1024, (dV) + 2048);   \
    k0 += (size_t)64 * 2048;                           \
    v0 += 64;                                          \
  } while (0)

  // QK^T (swapped operands) fused with exp + perm-packed P write, then PV
  // (+ ones-MFMA row-sum on the same P fragments).
#define COMPUTE(cK, cV)                                                                   \
  do {                                                                                    \
    _Pragma("unroll") for (int nt = 0; nt < 4; ++nt) {                                    \
      const int krow = nt * 16 + lr;                                                      \
      const short8 ka = ld_s8((const char*)(cK) + ((krow * 128 + quad * 16) ^ key));      \
      const short8 kb = ld_s8((const char*)(cK) + ((krow * 128 + 64 + quad * 16) ^ key)); \
      _Pragma("unroll") for (int t = 0; t < 2; ++t) {                                     \
        f32x4 z = {};                                                                     \
        z = MFMA16(ka, qf[t][0], z);                                                      \
        z = MFMA16(kb, qf[t][1], z);                                                      \
        const float e0 = __builtin_amdgcn_exp2f(fmaf(z[0], c1, -c2));                     \
        const float e1 = __builtin_amdgcn_exp2f(fmaf(z[1], c1, -c2));                     \
        const float e2 = __builtin_amdgcn_exp2f(fmaf(z[2], c1, -c2));                     \
        const float e3 = __builtin_amdgcn_exp2f(fmaf(z[3], c1, -c2));                     \
        uint2v pk;                                                                        \
        pk[0] = pk2_bf16(e0, e1);                                                         \
        pk[1] = pk2_bf16(e2, e3);                                                         \
        *(uint2v*)((char*)sPw + (((t * 16 + lr) * 128 + nt * 32 + quad * 8) ^ key)) = pk; \
      }                                                                                   \
    }                                                                                     \
    wave_fence();                                                                         \
    __builtin_amdgcn_s_setprio(1);                                                        \
    _Pragma("unroll") for (int ks = 0; ks < 2; ++ks) {                                    \
      const short8 p0 = ld_s8((const char*)sPw + ((lr * 128 + ks * 64 + quad * 16) ^ key)); \
      const short8 p1 = ld_s8((const char*)sPw + (((16 + lr) * 128 + ks * 64 + quad * 16) ^ key)); \
      _Pragma("unroll") for (int dt = 0; dt < 4; ++dt) {                                  \
        const short8 vv =                                                                 \
            ld_s8((const char*)(cV) + (((dt * 16 + lr) * 128 + ks * 64 + quad * 16) ^ key)); \
        o0[dt] = MFMA16(p0, vv, o0[dt]);                                                  \
        o1[dt] = MFMA16(p1, vv, o1[dt]);                                                  \
      }                                                                                   \
      ls0 = MFMA16(p0, onesb, ls0);                                                       \
      ls1 = MFMA16(p1, onesb, ls1);                                                       \
    }                                                                                     \
    __builtin_amdgcn_s_setprio(0);                                                        \
    wave_fence();                                                                         \
  } while (0)

  STAGE(dK0, dV0);  // tile 0 -> buf0

#pragma unroll 1
  for (int it2 = 0; it2 < 8; ++it2) {
    __syncthreads();            // drain+publish tile 2*it2 (buf0)
    STAGE(dK1, dV1);            // tile 2*it2+1 -> buf1
    COMPUTE(sK0, sV0);
    __syncthreads();            // drain+publish tile 2*it2+1 (buf1)
    if (it2 < 7) STAGE(dK0, dV0);  // tile 2*it2+2 -> buf0
    COMPUTE(sK1, sV1);
  }
#undef STAGE
#undef COMPUTE

#pragma unroll
  for (int t = 0; t < 2; ++t) {
    const f32x4 lt = t ? ls1 : ls0;   // lt[r] = rowsum of q-row quad*4+r (any col)
    const f32x4* oa = t ? o1 : o0;
    __hip_bfloat16* Og = O + ((size_t)b * 4096 + q0 + t * 16 + quad * 4) * 1024 + h * 64;
#pragma unroll
    for (int r = 0; r < 4; ++r) {
      const float rl = 1.0f / lt[r];
#pragma unroll
      for (int dt = 0; dt < 4; ++dt)
        st1((__hip_bfloat16*)&Og[(size_t)r * 1024 + dt * 16 + lr], oa[dt][r] * rl);
    }
  }
}

// ---------------- launch ----------------
extern "C" void kernel_launch(void* const* d_in, const int* in_sizes, int n_in,
                              void* d_out, int out_size, void* d_ws, size_t ws_size,
                              hipStream_t stream) {
  (void)in_sizes; (void)n_in; (void)out_size; (void)ws_size;
  const float* tokens  = (const float*)d_in[0];   // [4,4096,1024]
  const float* context = (const float*)d_in[1];   // [4,1024,768]
  const float* Wq = (const float*)d_in[2];        // [1024,1024] (in,out)
  const float* Wk = (const float*)d_in[3];        // [768,1024]
  const float* Wv = (const float*)d_in[4];        // [768,1024]
  const float* Wo = (const float*)d_in[5];        // [1024,1024]
  const float* bo = (const float*)d_in[6];        // [1024]
  float* out = (float*)d_out;                     // [4,4096,1024] fp32

  ushort_t* ws = (ushort_t*)d_ws;
  ushort_t* tokB = ws; ws += (size_t)16384 * 1024;
  ushort_t* ctxB = ws; ws += (size_t)4096 * 768;
  ushort_t* WqT  = ws; ws += (size_t)1024 * 1024;
  ushort_t* WkvT = ws; ws += (size_t)2048 * 768;   // rows 0..1023 Wk^T, 1024..2047 Wv^T
  ushort_t* WoT  = ws; ws += (size_t)1024 * 1024;
  ushort_t* Qb   = ws; ws += (size_t)16384 * 1024;
  ushort_t* KVb  = ws; ws += (size_t)4096 * 2048;
  ushort_t* Vt   = ws; ws += (size_t)4096 * 1024;
  ushort_t* Ab   = Qb;  // alias (safe: per-block read-then-write of same region)

  cvt_k<<<8192, 256, 0, stream>>>(tokens, tokB, (size_t)16384 * 1024 / 8);
  cvt_k<<<1536, 256, 0, stream>>>(context, ctxB, (size_t)4096 * 768 / 8);

  const dim3 tb(32, 8);
  transpose_cvt2_k<<<dim3(32, 32, 2), tb, 0, stream>>>(Wq, Wo, WqT, WoT, 1024, 1024);
  transpose_cvt2_k<<<dim3(32, 24, 2), tb, 0, stream>>>(Wk, Wv, WkvT, WkvT + (size_t)1024 * 768,
                                                       768, 1024);

  gemm_bt<__hip_bfloat16><<<dim3(8, 128), 256, 0, stream>>>(
      tokB, WqT, (__hip_bfloat16*)Qb, nullptr, 16384, 1024, 1024);
  kv_gemm<<<dim3(16, 32), 256, 0, stream>>>(ctxB, WkvT, KVb, Vt);

  attn_k<<<dim3(32, 16, 4), 256, 0, stream>>>(Qb, KVb, Vt, (__hip_bfloat16*)Ab);

  gemm_bt<float><<<dim3(8, 128), 256, 0, stream>>>(
      Ab, WoT, out, bo, 16384, 1024, 1024);
}

// Round 8
// 346.481 us; speedup vs baseline: 1.0794x; 1.0794x over previous
//
#include <hip/hip_runtime.h>
#include <hip/hip_bf16.h>
#include <math.h>

typedef unsigned short ushort_t;
typedef __attribute__((ext_vector_type(8))) short short8;
typedef __attribute__((ext_vector_type(4))) short short4v;
typedef __attribute__((ext_vector_type(4))) float f32x4;

#define MFMA16(a, b, c) __builtin_amdgcn_mfma_f32_16x16x32_bf16((a), (b), (c), 0, 0, 0)

__device__ __forceinline__ short8 ld_s8(const void* p) { return *(const short8*)p; }

// R5/R7 post-mortems: both hand-rolled bf16 converts (v_cvt_pk asm: wrong
// rounding -> absmax 0.51; add+v_perm half-up: MORE VALU, +17us) are BANNED.
// The compiler's __float2bfloat16 lowering is the best available.
__device__ __forceinline__ ushort_t f2bf(float x) {
  __hip_bfloat16 h = __float2bfloat16(x);
  return *reinterpret_cast<ushort_t*>(&h);
}

__device__ __forceinline__ void wave_fence() {
  __builtin_amdgcn_fence(__ATOMIC_ACQ_REL, "wavefront");
}

__device__ __forceinline__ void async_ld16(const void* g, void* l) {
  __builtin_amdgcn_global_load_lds(
      (const __attribute__((address_space(1))) unsigned int*)g,
      (__attribute__((address_space(3))) unsigned int*)l, 16, 0, 0);
}

// ---------------- fp32 -> bf16 elementwise convert (8 elems/thread) ----------------
__global__ __launch_bounds__(256) void cvt_k(const float* __restrict__ src,
                                             ushort_t* __restrict__ dst, size_t n8) {
  const size_t i = (size_t)blockIdx.x * 256 + threadIdx.x;
  if (i >= n8) return;
  const size_t base = i * 8;
  const float4 a = ((const float4*)(src + base))[0];
  const float4 b = ((const float4*)(src + base))[1];
  short8 o;
  o[0] = (short)f2bf(a.x); o[1] = (short)f2bf(a.y);
  o[2] = (short)f2bf(a.z); o[3] = (short)f2bf(a.w);
  o[4] = (short)f2bf(b.x); o[5] = (short)f2bf(b.y);
  o[6] = (short)f2bf(b.z); o[7] = (short)f2bf(b.w);
  *(short8*)(dst + base) = o;
}

// ---- batched fused transpose+convert: dst_z[C][R] = (bf16)src_z[R][C]^T, z in {0,1} ----
__global__ void transpose_cvt2_k(const float* __restrict__ s0, const float* __restrict__ s1,
                                 ushort_t* __restrict__ d0, ushort_t* __restrict__ d1,
                                 int R, int C) {
  __shared__ ushort_t tile[32][33];
  const float* src = blockIdx.z ? s1 : s0;
  ushort_t* dst = blockIdx.z ? d1 : d0;
  const int bx = blockIdx.x * 32, by = blockIdx.y * 32;
  const int tx = threadIdx.x, ty = threadIdx.y;
#pragma unroll
  for (int i = 0; i < 32; i += 8)
    tile[ty + i][tx] = f2bf(src[(size_t)(by + ty + i) * C + bx + tx]);
  __syncthreads();
#pragma unroll
  for (int i = 0; i < 32; i += 8)
    dst[(size_t)(bx + ty + i) * R + by + tx] = tile[tx][ty + i];
}

__device__ __forceinline__ void st1(float* p, float v) { *p = v; }
__device__ __forceinline__ void st1(__hip_bfloat16* p, float v) { *p = __float2bfloat16(v); }

__device__ __forceinline__ int2 xcd_swz(int nx) {
  const int id = blockIdx.y * gridDim.x + blockIdx.x;
  const int cpx = (gridDim.x * gridDim.y) >> 3;  // nwg divisible by 8
  const int nid = (id & 7) * cpx + (id >> 3);
  int2 r; r.x = nid % nx; r.y = nid / nx; return r;
}

// ================= 256x256 / BK=64 / 8-wave GEMM (R8, big projections) ==========
// R6-proven 2-phase sync scaled up: one barrier per K-tile, 1-deep prefetch,
// compile-time double buffers. 64 MFMA/wave between barriers (vs 16 at 128²),
// staged bytes per FLOP halved. LDS reads use the attn-proven (row&7)<<4 XOR
// swizzle with PRE-SWIZZLED global source (linear global_load_lds dest) --
// without it, 16 lanes reading stride-128B rows at one column 8-way conflict.
// LDS = 2 x (256x64 A + 256x64 B) x 2B = 128 KB -> 1 block/CU, 2 waves/SIMD.
// Accumulation order per output element unchanged -> bitwise-identical math.
#define GSTAGE256(sAx, sBx)                                                        \
  do {                                                                             \
    _Pragma("unroll") for (int r0 = 0; r0 < 4; ++r0) {                             \
      async_ld16(Ag + (size_t)(r0 * 64 + srow) * K + (k0 + scol), (sAx) + r0 * 4096 + wb); \
      async_ld16(Bg + (size_t)(r0 * 64 + srow) * K + (k0 + scol), (sBx) + r0 * 4096 + wb); \
    }                                                                              \
    k0 += 64;                                                                      \
  } while (0)

#define GCOMP256(sAx, sBx)                                                         \
  do {                                                                             \
    _Pragma("unroll") for (int kk = 0; kk < 2; ++kk) {                             \
      short8 bfr[4];                                                               \
      _Pragma("unroll") for (int tn = 0; tn < 4; ++tn) {                           \
        const int rb = wn + tn * 16 + lr;                                          \
        bfr[tn] = ld_s8((const char*)(sBx) + ((rb * 128 + kk * 64 + quad * 16) ^ key)); \
      }                                                                            \
      _Pragma("unroll") for (int tm = 0; tm < 8; ++tm) {                           \
        const int ra = wm + tm * 16 + lr;                                          \
        const short8 af = ld_s8((const char*)(sAx) + ((ra * 128 + kk * 64 + quad * 16) ^ key)); \
        _Pragma("unroll") for (int tn = 0; tn < 4; ++tn)                           \
          acc[tm][tn] = MFMA16(af, bfr[tn], acc[tm][tn]);                          \
      }                                                                            \
    }                                                                              \
  } while (0)

template <typename OutT>
__global__ __launch_bounds__(512, 1) void gemm256_bt(const ushort_t* __restrict__ A,
                                                     const ushort_t* __restrict__ Bt,
                                                     OutT* __restrict__ C,
                                                     const float* __restrict__ bias,
                                                     int M, int N, int K) {
  __shared__ __align__(16) ushort_t sA0[256 * 64];
  __shared__ __align__(16) ushort_t sA1[256 * 64];
  __shared__ __align__(16) ushort_t sB0[256 * 64];
  __shared__ __align__(16) ushort_t sB1[256 * 64];
  const int tid = threadIdx.x;
  const int lane = tid & 63, wave = tid >> 6;       // 8 waves
  const int lr = lane & 15, quad = lane >> 4;
  const int key = (lr & 7) << 4;                     // XOR-swizzle (rows == lr mod 8)
  const int2 bid = xcd_swz(gridDim.x);
  const int m0 = bid.y * 256, n0 = bid.x * 256;
  const int wm = (wave >> 2) * 128;                  // 2 M-groups of 128
  const int wn = (wave & 3) * 64;                    // 4 N-groups of 64
  const ushort_t* Ag = A + (size_t)m0 * K;
  const ushort_t* Bg = Bt + (size_t)n0 * K;
  // staging: linear LDS dest (per-wave base + lane*16B); pre-swizzled global col
  const int srow = tid >> 3;                         // 0..63 rows per issue
  const int scol = ((tid & 7) ^ (srow & 7)) * 8;     // swizzled 16B column (shorts)
  const int wb = (tid >> 6) * 512;                   // wave * 1KB (shorts)

  f32x4 acc[8][4] = {};
  int k0 = 0;

  GSTAGE256(sA0, sB0);     // tile 0 -> buf0
  const int NT2 = K >> 7;  // 2 K-tiles per iteration (K % 128 == 0)
#pragma unroll 1
  for (int i2 = 0; i2 < NT2; ++i2) {
    __syncthreads();                       // drain+publish even tile (buf0)
    GSTAGE256(sA1, sB1);                   // odd tile -> buf1
    GCOMP256(sA0, sB0);
    __syncthreads();                       // drain+publish odd tile (buf1)
    if (i2 < NT2 - 1) GSTAGE256(sA0, sB0); // next even tile -> buf0
    GCOMP256(sA1, sB1);
  }

#pragma unroll
  for (int tm = 0; tm < 8; ++tm) {
    const int row = m0 + wm + tm * 16 + quad * 4;
#pragma unroll
    for (int tn = 0; tn < 4; ++tn) {
      const int col = n0 + wn + tn * 16 + lr;
      const float bv = bias ? bias[col] : 0.0f;
#pragma unroll
      for (int r = 0; r < 4; ++r)
        st1(&C[(size_t)(row + r) * N + col], acc[tm][tn][r] + bv);
    }
  }
}

// ================= 128x128 / BK=32 2-phase GEMM (R6-proven, kv only) ============
#define BM 128
#define BN 128
#define BK 32

#define GSTAGE(sA, sB)                                          \
  do {                                                          \
    async_ld16(Ag + (size_t)srow * K + (k0 + scol), (sA) + wb); \
    async_ld16(Ag + (size_t)(srow + 64) * K + (k0 + scol), (sA) + 2048 + wb); \
    async_ld16(Bg + (size_t)srow * K + (k0 + scol), (sB) + wb); \
    async_ld16(Bg + (size_t)(srow + 64) * K + (k0 + scol), (sB) + 2048 + wb); \
    k0 += BK;                                                   \
  } while (0)

#define GCOMP(sA, sB)                                                     \
  do {                                                                    \
    short8 af[4], bfr[4];                                                 \
    _Pragma("unroll") for (int t = 0; t < 4; ++t) {                       \
      af[t] = ld_s8((sA) + (wm + t * 16 + lr) * BK + quad * 8);           \
      bfr[t] = ld_s8((sB) + (wn + t * 16 + lr) * BK + quad * 8);          \
    }                                                                     \
    _Pragma("unroll") for (int tm = 0; tm < 4; ++tm)                      \
        _Pragma("unroll") for (int tn = 0; tn < 4; ++tn)                  \
            acc[tm][tn] = MFMA16(af[tm], bfr[tn], acc[tm][tn]);           \
  } while (0)

// -------- fused K+V GEMM: A[4096,768] @ WkvT[2048,768]^T --------
// cols 0..1023 -> KVb[row][col] (K, row-major, stride 2048)
// cols 1024..2047 -> Vt[b][col-1024][m] (V transposed per batch)
__global__ __launch_bounds__(256) void kv_gemm(const ushort_t* __restrict__ A,
                                               const ushort_t* __restrict__ Bt,
                                               ushort_t* __restrict__ KVb,
                                               ushort_t* __restrict__ Vt) {
  const int K = 768;
  __shared__ __align__(16) ushort_t sA0[BM * BK];
  __shared__ __align__(16) ushort_t sA1[BM * BK];
  __shared__ __align__(16) ushort_t sB0[BN * BK];
  __shared__ __align__(16) ushort_t sB1[BN * BK];
  const int tid = threadIdx.x;
  const int lane = tid & 63, wave = tid >> 6;
  const int lr = lane & 15, quad = lane >> 4;
  const int2 bid = xcd_swz(gridDim.x);
  const int m0 = bid.y * BM, n0 = bid.x * BN;
  const int wm = (wave >> 1) * 64, wn = (wave & 1) * 64;
  const ushort_t* Ag = A + (size_t)m0 * K;
  const ushort_t* Bg = Bt + (size_t)n0 * K;
  const int srow = tid >> 2, scol = (tid & 3) * 8;
  const int wb = (tid & 192) * 8;

  f32x4 acc[4][4] = {};
  int k0 = 0;

  GSTAGE(sA0, sB0);
  const int NT2 = K >> 6;  // 12
#pragma unroll 1
  for (int i2 = 0; i2 < NT2; ++i2) {
    __syncthreads();
    GSTAGE(sA1, sB1);
    GCOMP(sA0, sB0);
    __syncthreads();
    if (i2 < NT2 - 1) GSTAGE(sA0, sB0);
    GCOMP(sA1, sB1);
  }

#pragma unroll
  for (int tm = 0; tm < 4; ++tm) {
    const int row = m0 + wm + tm * 16 + quad * 4;  // global context row
    const int b = row >> 10, mloc = row & 1023;
#pragma unroll
    for (int tn = 0; tn < 4; ++tn) {
      const int col = n0 + wn + tn * 16 + lr;  // block-uniform side of 1024
      if (col < 1024) {
#pragma unroll
        for (int r = 0; r < 4; ++r)
          KVb[(size_t)(row + r) * 2048 + col] = f2bf(acc[tm][tn][r]);
      } else {
        ushort_t* vp = Vt + ((size_t)b * 1024 + (col - 1024)) * 1024 + mloc;
#pragma unroll
        for (int r = 0; r < 4; ++r)
          vp[r] = f2bf(acc[tm][tn][r]);
      }
    }
  }
}

// ---------------- flash attention v7 (R6-proven, unchanged) ----------------
// grid (4096/128, 16 heads, 4 batch), 256 threads. Wave owns 32 q-rows.
// Swapped QK^T; ones-MFMA row-sum; dbuf + 2x unroll (compile-time buffers);
// XOR swizzle + pre-swizzled global source; setprio around PV MFMA cluster.
// LDS = 48 KB -> 3 blocks/CU.
__global__ __launch_bounds__(256) void attn_k(const ushort_t* __restrict__ Q,
                                              const ushort_t* __restrict__ KVb,
                                              const ushort_t* __restrict__ Vt,
                                              __hip_bfloat16* __restrict__ O) {
  __shared__ __align__(16) ushort_t sK0[64 * 64];
  __shared__ __align__(16) ushort_t sK1[64 * 64];
  __shared__ __align__(16) ushort_t sV0[64 * 64];
  __shared__ __align__(16) ushort_t sV1[64 * 64];
  __shared__ __align__(16) ushort_t sP[4 * 32 * 64];
  const int tid = threadIdx.x;
  const int lane = tid & 63, wave = tid >> 6;
  const int lr = lane & 15, quad = lane >> 4;
  const int b = blockIdx.z, h = blockIdx.y;
  const int q0 = blockIdx.x * 128 + wave * 32;
  const int key = (lr & 7) << 4;  // XOR-swizzle key; all read/write rows == lr (mod 8)

  const ushort_t* Qg = Q + ((size_t)b * 4096 + q0 + lr) * 1024 + h * 64;
  short8 qf[2][2];
#pragma unroll
  for (int t = 0; t < 2; ++t) {
    qf[t][0] = ld_s8(Qg + (size_t)t * 16 * 1024 + quad * 8);
    qf[t][1] = ld_s8(Qg + (size_t)t * 16 * 1024 + 32 + quad * 8);
  }
  const ushort_t* Kg = KVb + (size_t)b * 1024 * 2048 + h * 64;   // row stride 2048
  const ushort_t* Vg = Vt + ((size_t)b * 1024 + h * 64) * 1024;  // row stride 1024

  // staging: linear LDS dest (wave-uniform base + lane*16B), swizzled global col
  const int srow = lane >> 3;                // row within the wave's 8-row chunk
  const int scol = ((lane & 7) ^ srow) * 8;  // pre-swizzled 16B column (shorts)
  const ushort_t* k0 = Kg + (size_t)(wave * 8 + srow) * 2048 + scol;
  const ushort_t* v0 = Vg + (size_t)(wave * 8 + srow) * 1024 + scol;
  ushort_t* const dK0 = sK0 + wave * 512;
  ushort_t* const dK1 = sK1 + wave * 512;
  ushort_t* const dV0 = sV0 + wave * 512;
  ushort_t* const dV1 = sV1 + wave * 512;
  ushort_t* const sPw = sP + wave * 2048;  // 32 rows x 64 shorts, per-wave private

  const float c1 = 0.125f * 1.44269504f;
  const float c2 = 16.0f * 1.44269504f;

  // bf16 1.0 = 0x3F80 : ones B-fragment for the P.1 row-sum MFMA
  short8 onesb;
#pragma unroll
  for (int i = 0; i < 8; ++i) onesb[i] = (short)0x3F80;

  f32x4 ls0 = {}, ls1 = {};
  f32x4 o0[4] = {}, o1[4] = {};

#define STAGE(dK, dV)                                  \
  do {                                                 \
    async_ld16(k0, (dK));                              \
    async_ld16(k0 + (size_t)32 * 2048, (dK) + 2048);   \
    async_ld16(v0, (dV));                              \
    async_ld16(v0 + (size_t)32 * 1024, (dV) + 2048);   \
    k0 += (size_t)64 * 2048;                           \
    v0 += 64;                                          \
  } while (0)

  // QK^T (swapped operands) fused with exp + P write, then PV
  // (+ ones-MFMA row-sum on the same P fragments).
#define COMPUTE(cK, cV)                                                                   \
  do {                                                                                    \
    _Pragma("unroll") for (int nt = 0; nt < 4; ++nt) {                                    \
      const int krow = nt * 16 + lr;                                                      \
      const short8 ka = ld_s8((const char*)(cK) + ((krow * 128 + quad * 16) ^ key));      \
      const short8 kb = ld_s8((const char*)(cK) + ((krow * 128 + 64 + quad * 16) ^ key)); \
      _Pragma("unroll") for (int t = 0; t < 2; ++t) {                                     \
        f32x4 z = {};                                                                     \
        z = MFMA16(ka, qf[t][0], z);                                                      \
        z = MFMA16(kb, qf[t][1], z);                                                      \
        short4v pk;                                                                       \
        _Pragma("unroll") for (int r = 0; r < 4; ++r) {                                   \
          const float p = __builtin_amdgcn_exp2f(fmaf(z[r], c1, -c2));                    \
          pk[r] = (short)f2bf(p);                                                         \
        }                                                                                 \
        *(short4v*)((char*)sPw + (((t * 16 + lr) * 128 + nt * 32 + quad * 8) ^ key)) = pk;\
      }                                                                                   \
    }                                                                                     \
    wave_fence();                                                                         \
    __builtin_amdgcn_s_setprio(1);                                                        \
    _Pragma("unroll") for (int ks = 0; ks < 2; ++ks) {                                    \
      const short8 p0 = ld_s8((const char*)sPw + ((lr * 128 + ks * 64 + quad * 16) ^ key)); \
      const short8 p1 = ld_s8((const char*)sPw + (((16 + lr) * 128 + ks * 64 + quad * 16) ^ key)); \
      _Pragma("unroll") for (int dt = 0; dt < 4; ++dt) {                                  \
        const short8 vv =                                                                 \
            ld_s8((const char*)(cV) + (((dt * 16 + lr) * 128 + ks * 64 + quad * 16) ^ key)); \
        o0[dt] = MFMA16(p0, vv, o0[dt]);                                                  \
        o1[dt] = MFMA16(p1, vv, o1[dt]);                                                  \
      }                                                                                   \
      ls0 = MFMA16(p0, onesb, ls0);                                                       \
      ls1 = MFMA16(p1, onesb, ls1);                                                       \
    }                                                                                     \
    __builtin_amdgcn_s_setprio(0);                                                        \
    wave_fence();                                                                         \
  } while (0)

  STAGE(dK0, dV0);  // tile 0 -> buf0

#pragma unroll 1
  for (int it2 = 0; it2 < 8; ++it2) {
    __syncthreads();            // drain+publish tile 2*it2 (buf0)
    STAGE(dK1, dV1);            // tile 2*it2+1 -> buf1
    COMPUTE(sK0, sV0);
    __syncthreads();            // drain+publish tile 2*it2+1 (buf1)
    if (it2 < 7) STAGE(dK0, dV0);  // tile 2*it2+2 -> buf0
    COMPUTE(sK1, sV1);
  }
#undef STAGE
#undef COMPUTE

#pragma unroll
  for (int t = 0; t < 2; ++t) {
    const f32x4 lt = t ? ls1 : ls0;   // lt[r] = rowsum of q-row quad*4+r (any col)
    const f32x4* oa = t ? o1 : o0;
    __hip_bfloat16* Og = O + ((size_t)b * 4096 + q0 + t * 16 + quad * 4) * 1024 + h * 64;
#pragma unroll
    for (int r = 0; r < 4; ++r) {
      const float rl = 1.0f / lt[r];
#pragma unroll
      for (int dt = 0; dt < 4; ++dt)
        Og[(size_t)r * 1024 + dt * 16 + lr] = __float2bfloat16(oa[dt][r] * rl);
    }
  }
}

// ---------------- launch ----------------
extern "C" void kernel_launch(void* const* d_in, const int* in_sizes, int n_in,
                              void* d_out, int out_size, void* d_ws, size_t ws_size,
                              hipStream_t stream) {
  (void)in_sizes; (void)n_in; (void)out_size; (void)ws_size;
  const float* tokens  = (const float*)d_in[0];   // [4,4096,1024]
  const float* context = (const float*)d_in[1];   // [4,1024,768]
  const float* Wq = (const float*)d_in[2];        // [1024,1024] (in,out)
  const float* Wk = (const float*)d_in[3];        // [768,1024]
  const float* Wv = (const float*)d_in[4];        // [768,1024]
  const float* Wo = (const float*)d_in[5];        // [1024,1024]
  const float* bo = (const float*)d_in[6];        // [1024]
  float* out = (float*)d_out;                     // [4,4096,1024] fp32

  ushort_t* ws = (ushort_t*)d_ws;
  ushort_t* tokB = ws; ws += (size_t)16384 * 1024;
  ushort_t* ctxB = ws; ws += (size_t)4096 * 768;
  ushort_t* WqT  = ws; ws += (size_t)1024 * 1024;
  ushort_t* WkvT = ws; ws += (size_t)2048 * 768;   // rows 0..1023 Wk^T, 1024..2047 Wv^T
  ushort_t* WoT  = ws; ws += (size_t)1024 * 1024;
  ushort_t* Qb   = ws; ws += (size_t)16384 * 1024;
  ushort_t* KVb  = ws; ws += (size_t)4096 * 2048;
  ushort_t* Vt   = ws; ws += (size_t)4096 * 1024;
  ushort_t* Ab   = Qb;  // alias (safe: per-block read-then-write of same region)

  cvt_k<<<8192, 256, 0, stream>>>(tokens, tokB, (size_t)16384 * 1024 / 8);
  cvt_k<<<1536, 256, 0, stream>>>(context, ctxB, (size_t)4096 * 768 / 8);

  const dim3 tb(32, 8);
  transpose_cvt2_k<<<dim3(32, 32, 2), tb, 0, stream>>>(Wq, Wo, WqT, WoT, 1024, 1024);
  transpose_cvt2_k<<<dim3(32, 24, 2), tb, 0, stream>>>(Wk, Wv, WkvT, WkvT + (size_t)1024 * 768,
                                                       768, 1024);

  gemm256_bt<__hip_bfloat16><<<dim3(4, 64), 512, 0, stream>>>(
      tokB, WqT, (__hip_bfloat16*)Qb, nullptr, 16384, 1024, 1024);
  kv_gemm<<<dim3(16, 32), 256, 0, stream>>>(ctxB, WkvT, KVb, Vt);

  attn_k<<<dim3(32, 16, 4), 256, 0, stream>>>(Qb, KVb, Vt, (__hip_bfloat16*)Ab);

  gemm256_bt<float><<<dim3(4, 64), 512, 0, stream>>>(
      Ab, WoT, out, bo, 16384, 1024, 1024);
}